// Round 1
// baseline (715.249 us; speedup 1.0000x reference)
//
#include <hip/hip_runtime.h>
#include <hip/hip_bf16.h>

typedef __bf16 bf16x8 __attribute__((ext_vector_type(8)));
typedef float f32x4 __attribute__((ext_vector_type(4)));

#define MFMA16(A, B, C) __builtin_amdgcn_mfma_f32_16x16x32_bf16((A), (B), (C), 0, 0, 0)

namespace {
constexpr int kT = 256, kIN = 128, kHZ = 24;
constexpr int kRB = 16;   // batch rows per block
}

__device__ __forceinline__ float fsig(float v) {
  float e = __builtin_amdgcn_exp2f(-1.44269504088896340736f * v);
  return __builtin_amdgcn_rcpf(1.0f + e);
}
__device__ __forceinline__ float ftanh(float v) {
  float e = __builtin_amdgcn_exp2f(2.88539008177792681472f * v);
  return 1.0f - 2.0f * __builtin_amdgcn_rcpf(e + 1.0f);
}

// -------------------- main fused GRU kernel --------------------
// 64 blocks x 256 threads (4 waves). Each block owns 16 batch rows for all
// 256 steps. Weights live in registers as bf16 MFMA B-fragments. h lives in
// LDS (fp32 exact copy + bf16 XOR-swizzled copy for ds_read_b128 A-frags).
// Output sum_t h_t @ N_t accumulates in registers (2 MFMA/wave/step).
__global__ __launch_bounds__(256, 1) void gru_main(
    const float* __restrict__ x, const float* __restrict__ w_i,
    const float* __restrict__ w_h, const float* __restrict__ bias,
    const __bf16* __restrict__ Nfrag, const float* __restrict__ cvec,
    float* __restrict__ out)
{
  const int tid = threadIdx.x;
  const int w = tid >> 6;      // wave 0..3
  const int l = tid & 63;
  const int lrow = l & 15;     // A-row / B-col / C-col lane index
  const int lg = l >> 4;       // k-group
  const int b0 = blockIdx.x * kRB;

  __shared__ float h_f32[16][132];
  __shared__ float zbuf[16][132];
  __shared__ __align__(16) __bf16 h_bf[16 * 128];   // XOR-swizzled
  __shared__ __align__(16) __bf16 rh_bf[16 * 128];  // XOR-swizzled
  __shared__ __align__(16) float red[4][64][4];

  for (int i = tid; i < 16 * 132; i += 256) { ((float*)h_f32)[i] = 0.0f; ((float*)zbuf)[i] = 0.0f; }
  for (int i = tid; i < 16 * 128; i += 256) { h_bf[i] = (__bf16)0.0f; rh_bf[i] = (__bf16)0.0f; }

  // ---- persistent weight fragments (bf16), combined K = [x(128); h(128)] ----
  // GEMM1 (zr): this wave owns cols [64w, 64w+64) of 256.
  // GEMM2 (a):  this wave owns cols [32w, 32w+32) of 128 (w_* cols 256+...).
  bf16x8 Wzr[8][4];
  bf16x8 Wa[8][2];
#pragma unroll
  for (int kc = 0; kc < 8; ++kc) {
#pragma unroll
    for (int nt = 0; nt < 4; ++nt) {
      const int col = w * 64 + nt * 16 + lrow;
      bf16x8 f;
#pragma unroll
      for (int e = 0; e < 8; ++e) {
        const int k = kc * 32 + lg * 8 + e;
        const float v = (k < 128) ? w_i[k * 384 + col] : w_h[(k - 128) * 384 + col];
        f[e] = (__bf16)v;
      }
      Wzr[kc][nt] = f;
    }
  }
#pragma unroll
  for (int kc = 0; kc < 8; ++kc) {
#pragma unroll
    for (int nt = 0; nt < 2; ++nt) {
      const int col = 256 + w * 32 + nt * 16 + lrow;
      bf16x8 f;
#pragma unroll
      for (int e = 0; e < 8; ++e) {
        const int k = kc * 32 + lg * 8 + e;
        const float v = (k < 128) ? w_i[k * 384 + col] : w_h[(k - 128) * 384 + col];
        f[e] = (__bf16)v;
      }
      Wa[kc][nt] = f;
    }
  }

  float bz[4], ba[2];
#pragma unroll
  for (int nt = 0; nt < 4; ++nt) bz[nt] = bias[w * 64 + nt * 16 + lrow];
#pragma unroll
  for (int nt = 0; nt < 2; ++nt) ba[nt] = bias[256 + w * 32 + nt * 16 + lrow];

  // output accumulation assignment: ntile = w&1, k-chunks {w&2, (w&2)+1}
  const int kcA = (w & 2);
  const __bf16* nbase = Nfrag + (size_t)(w & 1) * 512 + (size_t)l * 8;

  const float* xbase = x + ((size_t)(b0 + lrow)) * kT * kIN + lg * 8;

  f32x4 oacc = {0.f, 0.f, 0.f, 0.f};
  bf16x8 nfA, nfB;
#pragma unroll
  for (int e = 0; e < 8; ++e) { nfA[e] = (__bf16)0.0f; nfB[e] = (__bf16)0.0f; }
  bf16x8 xf[4], hf[4], rf[4];
  float4 xpre[8];

  // prefetch + convert x for t = 0
#pragma unroll
  for (int kc = 0; kc < 4; ++kc) {
    const float4* p = (const float4*)(xbase + kc * 32);
    xpre[2 * kc] = p[0];
    xpre[2 * kc + 1] = p[1];
  }
#pragma unroll
  for (int kc = 0; kc < 4; ++kc) {
    bf16x8 f;
    f[0] = (__bf16)xpre[2*kc].x;   f[1] = (__bf16)xpre[2*kc].y;
    f[2] = (__bf16)xpre[2*kc].z;   f[3] = (__bf16)xpre[2*kc].w;
    f[4] = (__bf16)xpre[2*kc+1].x; f[5] = (__bf16)xpre[2*kc+1].y;
    f[6] = (__bf16)xpre[2*kc+1].z; f[7] = (__bf16)xpre[2*kc+1].w;
    xf[kc] = f;
  }

  __syncthreads();

#pragma unroll 1
  for (int t = 0; t < kT; ++t) {
    // ---- A-fragments of h_{t-1} (bf16, swizzled LDS) ----
#pragma unroll
    for (int kc = 0; kc < 4; ++kc) {
      const int idx = (lrow * 128 + kc * 32 + lg * 8) ^ ((lrow & 7) << 3);
      hf[kc] = *(const bf16x8*)(h_bf + idx);
    }
    // ---- fused output accumulation: h_{t-1} @ N_{t-1} ----
    if (t > 0) {
      bf16x8 hA, hB;
      if (w & 2) { hA = hf[2]; hB = hf[3]; } else { hA = hf[0]; hB = hf[1]; }
      oacc = MFMA16(hA, nfA, oacc);
      oacc = MFMA16(hB, nfB, oacc);
    }
    // prefetch N_t fragments (used next iteration)
    {
      const __bf16* np = nbase + (size_t)t * 4096 + (size_t)kcA * 1024;
      nfA = *(const bf16x8*)(np);
      nfB = *(const bf16x8*)(np + 1024);
    }
    // prefetch x_{t+1}
    {
      const int tn = (t < kT - 1) ? (t + 1) : t;
#pragma unroll
      for (int kc = 0; kc < 4; ++kc) {
        const float4* p = (const float4*)(xbase + (size_t)tn * kIN + kc * 32);
        xpre[2 * kc] = p[0];
        xpre[2 * kc + 1] = p[1];
      }
    }
    // ---- GEMM1: pre_zr = [x;h] @ [w_i_zr; w_h_zr] + b_zr ----
    f32x4 acc1[4];
#pragma unroll
    for (int nt = 0; nt < 4; ++nt) { f32x4 a = {bz[nt], bz[nt], bz[nt], bz[nt]}; acc1[nt] = a; }
#pragma unroll
    for (int kc = 0; kc < 4; ++kc) {
#pragma unroll
      for (int nt = 0; nt < 4; ++nt) acc1[nt] = MFMA16(xf[kc], Wzr[kc][nt], acc1[nt]);
    }
#pragma unroll
    for (int kc = 0; kc < 4; ++kc) {
#pragma unroll
      for (int nt = 0; nt < 4; ++nt) acc1[nt] = MFMA16(hf[kc], Wzr[kc + 4][nt], acc1[nt]);
    }
    // ---- sigmoid; waves 0-1 produce z (cols 0..127), waves 2-3 produce r*h ----
    if (w < 2) {
#pragma unroll
      for (int nt = 0; nt < 4; ++nt) {
#pragma unroll
        for (int r = 0; r < 4; ++r) {
          const int row = lg * 4 + r;
          const int col = w * 64 + nt * 16 + lrow;
          zbuf[row][col] = fsig(acc1[nt][r]);
        }
      }
    } else {
#pragma unroll
      for (int nt = 0; nt < 4; ++nt) {
#pragma unroll
        for (int r = 0; r < 4; ++r) {
          const int row = lg * 4 + r;
          const int cr = (w - 2) * 64 + nt * 16 + lrow;
          const float s = fsig(acc1[nt][r]);
          const float rh = s * h_f32[row][cr];
          rh_bf[(row * 128 + cr) ^ ((row & 7) << 3)] = (__bf16)rh;
        }
      }
    }
    __syncthreads();
    // ---- GEMM2: pre_a = [x; r*h] @ [w_i_a; w_h_a] + b_a ----
#pragma unroll
    for (int kc = 0; kc < 4; ++kc) {
      const int idx = (lrow * 128 + kc * 32 + lg * 8) ^ ((lrow & 7) << 3);
      rf[kc] = *(const bf16x8*)(rh_bf + idx);
    }
    f32x4 acc2[2];
#pragma unroll
    for (int nt = 0; nt < 2; ++nt) { f32x4 a = {ba[nt], ba[nt], ba[nt], ba[nt]}; acc2[nt] = a; }
#pragma unroll
    for (int kc = 0; kc < 4; ++kc) {
#pragma unroll
      for (int nt = 0; nt < 2; ++nt) acc2[nt] = MFMA16(xf[kc], Wa[kc][nt], acc2[nt]);
    }
#pragma unroll
    for (int kc = 0; kc < 4; ++kc) {
#pragma unroll
      for (int nt = 0; nt < 2; ++nt) acc2[nt] = MFMA16(rf[kc], Wa[kc + 4][nt], acc2[nt]);
    }
    // convert x_{t+1} fragments (overlaps GEMM2 latency)
#pragma unroll
    for (int kc = 0; kc < 4; ++kc) {
      bf16x8 f;
      f[0] = (__bf16)xpre[2*kc].x;   f[1] = (__bf16)xpre[2*kc].y;
      f[2] = (__bf16)xpre[2*kc].z;   f[3] = (__bf16)xpre[2*kc].w;
      f[4] = (__bf16)xpre[2*kc+1].x; f[5] = (__bf16)xpre[2*kc+1].y;
      f[6] = (__bf16)xpre[2*kc+1].z; f[7] = (__bf16)xpre[2*kc+1].w;
      xf[kc] = f;
    }
    // ---- tanh + gated blend; each wave owns h cols [32w, 32w+32) ----
#pragma unroll
    for (int nt = 0; nt < 2; ++nt) {
#pragma unroll
      for (int r = 0; r < 4; ++r) {
        const int row = lg * 4 + r;
        const int col = w * 32 + nt * 16 + lrow;
        const float a = ftanh(acc2[nt][r]);
        const float hold = h_f32[row][col];
        const float z = zbuf[row][col];
        const float hn = fmaf(z, a - hold, hold);
        h_f32[row][col] = hn;
        h_bf[(row * 128 + col) ^ ((row & 7) << 3)] = (__bf16)hn;
      }
    }
    __syncthreads();
  }

  // ---- epilogue: last term h_{T-1} @ N_{T-1}, cross-wave K reduce, store ----
#pragma unroll
  for (int kc = 0; kc < 4; ++kc) {
    const int idx = (lrow * 128 + kc * 32 + lg * 8) ^ ((lrow & 7) << 3);
    hf[kc] = *(const bf16x8*)(h_bf + idx);
  }
  {
    bf16x8 hA, hB;
    if (w & 2) { hA = hf[2]; hB = hf[3]; } else { hA = hf[0]; hB = hf[1]; }
    oacc = MFMA16(hA, nfA, oacc);
    oacc = MFMA16(hB, nfB, oacc);
  }
  *(f32x4*)(&red[w][l][0]) = oacc;
  __syncthreads();
  if (w < 2) {
#pragma unroll
    for (int r = 0; r < 4; ++r) {
      const int row = lg * 4 + r;
      const int col = w * 16 + lrow;
      if (col < kHZ) {
        const float v = red[w][l][r] + red[w + 2][l][r] + cvec[col];
        out[(size_t)(b0 + row) * kHZ + col] = v;
      }
    }
  }
}

// -------------------- N_t = mlp_w @ (fc_w_t @ out_w), stored as bf16 B-frags --------------------
__global__ __launch_bounds__(256) void nprep(
    const float* __restrict__ mlp_w, const float* __restrict__ fc_w,
    const float* __restrict__ out_w, __bf16* __restrict__ Nfrag)
{
  const int t = blockIdx.x;
  const int tid = threadIdx.x;
  __shared__ __align__(16) float Q[512 * 24];   // 48 KiB
  __shared__ __align__(16) float obuf[4096];    // 16 KiB: ow (phase1) / Nb[128][32] (phase3)

  float* ow = obuf;
  for (int i = tid; i < 128 * 24; i += 256) ow[i] = out_w[i];
  __syncthreads();

  // phase 1: Q[i][j] = sum_m fc_w[t*512+i, m] * out_w[m, j]
  for (int i = tid; i < 512; i += 256) {
    const float* rowp = fc_w + ((size_t)t * 512 + i) * 128;
    float q[24];
#pragma unroll
    for (int j = 0; j < 24; ++j) q[j] = 0.0f;
    auto acc_m = [&](float rv, int m) {
      const float4* owp = (const float4*)(ow + m * 24);
      const float4 o0 = owp[0], o1 = owp[1], o2 = owp[2];
      const float4 o3 = owp[3], o4 = owp[4], o5 = owp[5];
      q[0]  = fmaf(rv, o0.x, q[0]);  q[1]  = fmaf(rv, o0.y, q[1]);
      q[2]  = fmaf(rv, o0.z, q[2]);  q[3]  = fmaf(rv, o0.w, q[3]);
      q[4]  = fmaf(rv, o1.x, q[4]);  q[5]  = fmaf(rv, o1.y, q[5]);
      q[6]  = fmaf(rv, o1.z, q[6]);  q[7]  = fmaf(rv, o1.w, q[7]);
      q[8]  = fmaf(rv, o2.x, q[8]);  q[9]  = fmaf(rv, o2.y, q[9]);
      q[10] = fmaf(rv, o2.z, q[10]); q[11] = fmaf(rv, o2.w, q[11]);
      q[12] = fmaf(rv, o3.x, q[12]); q[13] = fmaf(rv, o3.y, q[13]);
      q[14] = fmaf(rv, o3.z, q[14]); q[15] = fmaf(rv, o3.w, q[15]);
      q[16] = fmaf(rv, o4.x, q[16]); q[17] = fmaf(rv, o4.y, q[17]);
      q[18] = fmaf(rv, o4.z, q[18]); q[19] = fmaf(rv, o4.w, q[19]);
      q[20] = fmaf(rv, o5.x, q[20]); q[21] = fmaf(rv, o5.y, q[21]);
      q[22] = fmaf(rv, o5.z, q[22]); q[23] = fmaf(rv, o5.w, q[23]);
    };
#pragma unroll 4
    for (int m4 = 0; m4 < 32; ++m4) {
      const float4 rv = *(const float4*)(rowp + m4 * 4);
      acc_m(rv.x, m4 * 4 + 0);
      acc_m(rv.y, m4 * 4 + 1);
      acc_m(rv.z, m4 * 4 + 2);
      acc_m(rv.w, m4 * 4 + 3);
    }
#pragma unroll
    for (int j = 0; j < 24; ++j) Q[i * 24 + j] = q[j];
  }
  __syncthreads();

  // phase 2: N[i][j] = sum_k mlp_w[i, k] * Q[k][j]   (obuf becomes Nb[128][32])
  {
    const int i = tid & 127;
    const int jh = tid >> 7;
    const float* mrow = mlp_w + (size_t)i * 512;
    float q[12];
#pragma unroll
    for (int j = 0; j < 12; ++j) q[j] = 0.0f;
    auto acc_k = [&](float mv, int k) {
      const float* qrow = Q + (size_t)k * 24 + jh * 12;
      const float4 q0 = *(const float4*)(qrow);
      const float4 q1 = *(const float4*)(qrow + 4);
      const float4 q2 = *(const float4*)(qrow + 8);
      q[0]  = fmaf(mv, q0.x, q[0]);  q[1]  = fmaf(mv, q0.y, q[1]);
      q[2]  = fmaf(mv, q0.z, q[2]);  q[3]  = fmaf(mv, q0.w, q[3]);
      q[4]  = fmaf(mv, q1.x, q[4]);  q[5]  = fmaf(mv, q1.y, q[5]);
      q[6]  = fmaf(mv, q1.z, q[6]);  q[7]  = fmaf(mv, q1.w, q[7]);
      q[8]  = fmaf(mv, q2.x, q[8]);  q[9]  = fmaf(mv, q2.y, q[9]);
      q[10] = fmaf(mv, q2.z, q[10]); q[11] = fmaf(mv, q2.w, q[11]);
    };
#pragma unroll 2
    for (int k4 = 0; k4 < 128; ++k4) {
      const float4 mv = *(const float4*)(mrow + k4 * 4);
      acc_k(mv.x, k4 * 4 + 0);
      acc_k(mv.y, k4 * 4 + 1);
      acc_k(mv.z, k4 * 4 + 2);
      acc_k(mv.w, k4 * 4 + 3);
    }
    float* Nb = obuf;  // ow is dead past the first barrier
#pragma unroll
    for (int j = 0; j < 12; ++j) Nb[i * 32 + jh * 12 + j] = q[j];
  }
  for (int idx = tid; idx < 128 * 8; idx += 256) obuf[(idx >> 3) * 32 + 24 + (idx & 7)] = 0.0f;
  __syncthreads();

  // phase 3: emit bf16 B-fragments, layout [t][kc(4)][nt(2)][lane(64)][e(8)]
  {
    const float* Nb = obuf;
#pragma unroll
    for (int u = 0; u < 16; ++u) {
      const int f = tid * 16 + u;
      const int e = f & 7;
      const int lane = (f >> 3) & 63;
      const int nt = (f >> 9) & 1;
      const int kc = f >> 10;
      const int k = kc * 32 + (lane >> 4) * 8 + e;
      const int colj = nt * 16 + (lane & 15);
      Nfrag[(size_t)t * 4096 + f] = (__bf16)Nb[k * 32 + colj];
    }
  }
}

// -------------------- bias constant: partial[r0][m] = sum_i mlp_b[i]*fc_w[r0*512+i, m] ----
__global__ __launch_bounds__(256) void bias_partial(
    const float* __restrict__ mlp_b, const float* __restrict__ fc_w,
    float* __restrict__ partial)
{
  const int r0 = blockIdx.x;
  const int tid = threadIdx.x;
  const int m = tid & 127;
  const int g = tid >> 7;
  __shared__ int anynz;
  if (tid == 0) anynz = 0;
  __syncthreads();
  {
    int nz = 0;
    for (int i = tid; i < 512; i += 256) nz |= (mlp_b[i] != 0.0f) ? 1 : 0;
    if (nz) atomicOr(&anynz, 1);
  }
  __syncthreads();
  float acc = 0.0f;
  if (anynz) {
    for (int i = g; i < 512; i += 2)
      acc = fmaf(mlp_b[i], fc_w[((size_t)r0 * 512 + i) * 128 + m], acc);
  }
  __shared__ float sred[2][128];
  sred[g][m] = acc;
  __syncthreads();
  if (g == 0) partial[r0 * 128 + m] = sred[0][m] + sred[1][m];
}

__global__ __launch_bounds__(128) void bias_final(
    const float* __restrict__ fc_b, const float* __restrict__ out_b,
    const float* __restrict__ out_w, const float* __restrict__ partial,
    float* __restrict__ cvec)
{
  const int m = threadIdx.x;  // 128 threads
  float s = fc_b[m];
  for (int r0 = 0; r0 < 256; ++r0) s += partial[r0 * 128 + m];
  __shared__ float sm[128];
  sm[m] = s;
  __syncthreads();
  if (m < kHZ) {
    float c = out_b[m];
    for (int k = 0; k < 128; ++k) c = fmaf(sm[k], out_w[k * kHZ + m], c);
    cvec[m] = c;
  }
}

extern "C" void kernel_launch(void* const* d_in, const int* in_sizes, int n_in,
                              void* d_out, int out_size, void* d_ws, size_t ws_size,
                              hipStream_t stream) {
  (void)in_sizes; (void)n_in; (void)out_size; (void)ws_size;
  const float* x     = (const float*)d_in[0];
  const float* w_i   = (const float*)d_in[1];
  const float* w_h   = (const float*)d_in[2];
  const float* bias  = (const float*)d_in[3];
  const float* mlp_w = (const float*)d_in[4];
  const float* mlp_b = (const float*)d_in[5];
  const float* fc_w  = (const float*)d_in[6];
  const float* fc_b  = (const float*)d_in[7];
  const float* out_w = (const float*)d_in[8];
  const float* out_b = (const float*)d_in[9];
  float* out = (float*)d_out;

  // workspace: Nfrag (2 MiB bf16) | partial (128 KiB) | cvec (96 B)  -> ~2.25 MiB
  __bf16* Nfrag  = (__bf16*)d_ws;
  float* partial = (float*)((char*)d_ws + (size_t)256 * 4096 * 2);
  float* cvec    = (float*)((char*)d_ws + (size_t)256 * 4096 * 2 + 256 * 128 * 4);

  nprep<<<256, 256, 0, stream>>>(mlp_w, fc_w, out_w, Nfrag);
  bias_partial<<<256, 256, 0, stream>>>(mlp_b, fc_w, partial);
  bias_final<<<1, 128, 0, stream>>>(fc_b, out_b, out_w, partial, cvec);
  gru_main<<<64, 256, 0, stream>>>(x, w_i, w_h, bias, Nfrag, cvec, out);
}